// Round 8
// baseline (98.725 us; speedup 1.0000x reference)
//
#include <hip/hip_runtime.h>
#include <math.h>

// Renderer: occupancy-field ray marching + secant + shading.
// R14: LDS halving + scalar-path weights + uniform branches.
//     Arithmetic: R13 phase-3 issued 384 ds_read_b128/wave; at ~12cy on the
//     shared per-CU LDS pipe x16 waves/CU = ~74k cyc = ~31us = observed
//     kernel time -> LDS-pipe-bound. Changes:
//     (1) LDS keeps only ray-DEPENDENT tables sP0{a,a',c,c'}, sC{aC,aC',cC,cC'}
//         -> 2 b128/slot (was 4).
//     (2) ray-INDEPENDENT W2/Wc2 read with uniform index from global ->
//         s_load via scalar cache (no LDS, no vector VMEM). LN2 folded at
//         epilogue. SO/A accumulators scalarized (1 SGPR per v_fma).
//     (3) wave-uniform branches (dfar==0, l0>=0, crossed, msk, obj) wrapped
//         in readfirstlane -> compiler emits scalar branches + enables
//         uniformity-driven s_load inside them.
// Carried from R13: hw-log softplus (exact), logit-sign crossing search.
// Carried from R7: early-exit chunked march, in-register bookkeeping,
//     dfar==0 fast path, in-register 96-sample compositing scan.

namespace {

constexpr int H_    = 128;
constexpr int RS    = 128;   // RAY_STEPS
constexpr int NSEC  = 8;
constexpr int SOUT_ = 32;    // STEPS_OUT
constexpr int SIN_  = 64;    // STEPS_IN
constexpr int FULL_ = 96;
constexpr float EPSA   = 1e-6f;
constexpr float DELTA_ = 0.44626032029685964f; // max(2*exp(-1.5), 0.1)
constexpr float L2E    = 1.4426950408889634f;  // log2(e)
constexpr float LN2    = 0.6931471805599453f;

typedef __attribute__((ext_vector_type(2))) float f2;

__device__ __forceinline__ f2 s2(float v) { return f2{v, v}; }

// packed log2-domain softplus: sp2(u) = max(u,0) + log2(1 + 2^-|u|)
// exact: e = 2^-|u| in (0,1], 1+e in (1,2], v_log_f32 is ~1ulp there.
__device__ __forceinline__ f2 sp2p(f2 u) {
    f2 e;
    e.x = __builtin_amdgcn_exp2f(-fabsf(u.x));
    e.y = __builtin_amdgcn_exp2f(-fabsf(u.y));
    f2 onep = e + 1.0f;
    f2 l;
    l.x = __builtin_amdgcn_logf(onep.x);   // v_log_f32 = log2
    l.y = __builtin_amdgcn_logf(onep.y);
    return __builtin_elementwise_max(u, s2(0.0f)) + l;
}

__device__ __forceinline__ float sigmoid_fast(float x) {
    return __builtin_amdgcn_rcpf(1.0f + __expf(-x));
}
__device__ __forceinline__ float sgnf(float p) {
    return (p > 0.0f) ? 1.0f : ((p < 0.0f) ? -1.0f : 0.0f);
}
__device__ __forceinline__ float secant_step(float f_l, float f_h, float d_l, float d_h) {
    float den = f_h - f_l;
    if (fabsf(den) > 1e-12f) return -f_l * (d_h - d_l) / den + d_l;
    return 0.5f * (d_l + d_h);
}
__device__ __forceinline__ float2 ld2(const float* p) {
    return *reinterpret_cast<const float2*>(p);
}
// wave-uniform value -> SGPR (semantics-preserving: 1 ray per wave)
__device__ __forceinline__ float rflf(float x) {
    return __uint_as_float(__builtin_amdgcn_readfirstlane(__float_as_uint(x)));
}
__device__ __forceinline__ int rfli(int x) {
    return __builtin_amdgcn_readfirstlane(x);
}

__device__ void inv4(const float* m, float* o) {
    float inv[16];
    inv[0]  =  m[5]*m[10]*m[15] - m[5]*m[11]*m[14] - m[9]*m[6]*m[15] + m[9]*m[7]*m[14] + m[13]*m[6]*m[11] - m[13]*m[7]*m[10];
    inv[4]  = -m[4]*m[10]*m[15] + m[4]*m[11]*m[14] + m[8]*m[6]*m[15] - m[8]*m[7]*m[14] - m[12]*m[6]*m[11] + m[12]*m[7]*m[10];
    inv[8]  =  m[4]*m[9]*m[15]  - m[4]*m[11]*m[13] - m[8]*m[5]*m[15] + m[8]*m[7]*m[13] + m[12]*m[5]*m[11] - m[12]*m[7]*m[9];
    inv[12] = -m[4]*m[9]*m[14]  + m[4]*m[10]*m[13] + m[8]*m[5]*m[14] - m[8]*m[6]*m[13] - m[12]*m[5]*m[10] + m[12]*m[6]*m[9];
    inv[1]  = -m[1]*m[10]*m[15] + m[1]*m[11]*m[14] + m[9]*m[2]*m[15] - m[9]*m[3]*m[14] - m[13]*m[2]*m[11] + m[13]*m[3]*m[10];
    inv[5]  =  m[0]*m[10]*m[15] - m[0]*m[11]*m[14] - m[8]*m[2]*m[15] + m[8]*m[3]*m[14] + m[12]*m[2]*m[11] - m[12]*m[3]*m[10];
    inv[9]  = -m[0]*m[9]*m[15]  + m[0]*m[11]*m[13] + m[8]*m[1]*m[15] - m[8]*m[3]*m[13] - m[12]*m[1]*m[11] + m[12]*m[3]*m[9];
    inv[13] =  m[0]*m[9]*m[14]  - m[0]*m[10]*m[13] - m[8]*m[1]*m[14] + m[8]*m[2]*m[13] + m[12]*m[1]*m[10] - m[12]*m[2]*m[9];
    inv[2]  =  m[1]*m[6]*m[15]  - m[1]*m[7]*m[14]  - m[5]*m[2]*m[15] + m[5]*m[3]*m[14] + m[13]*m[2]*m[7]  - m[13]*m[3]*m[6];
    inv[6]  = -m[0]*m[6]*m[15]  + m[0]*m[7]*m[14]  + m[4]*m[2]*m[15] - m[4]*m[3]*m[14] - m[12]*m[2]*m[7]  + m[12]*m[3]*m[6];
    inv[10] =  m[0]*m[5]*m[15]  - m[0]*m[7]*m[13]  - m[4]*m[1]*m[15] + m[4]*m[3]*m[13] + m[12]*m[1]*m[7]  - m[12]*m[3]*m[5];
    inv[14] = -m[0]*m[5]*m[14]  + m[0]*m[6]*m[13]  + m[4]*m[1]*m[14] - m[4]*m[2]*m[13] - m[12]*m[1]*m[6]  + m[12]*m[2]*m[5];
    inv[3]  = -m[1]*m[6]*m[11]  + m[1]*m[7]*m[10]  + m[5]*m[2]*m[11] - m[5]*m[3]*m[10] - m[9]*m[2]*m[7]   + m[9]*m[3]*m[6];
    inv[7]  =  m[0]*m[6]*m[11]  - m[0]*m[7]*m[10]  - m[4]*m[2]*m[11] + m[4]*m[3]*m[10] + m[8]*m[2]*m[7]   - m[8]*m[3]*m[6];
    inv[11] = -m[0]*m[5]*m[11]  + m[0]*m[7]*m[9]   + m[4]*m[1]*m[11] - m[4]*m[3]*m[9]  - m[8]*m[1]*m[7]   + m[8]*m[3]*m[5];
    inv[15] =  m[0]*m[5]*m[10]  - m[0]*m[6]*m[9]   - m[4]*m[1]*m[10] + m[4]*m[2]*m[9]  + m[8]*m[1]*m[6]   - m[8]*m[2]*m[5];
    float det = m[0]*inv[0] + m[1]*inv[4] + m[2]*inv[8] + m[3]*inv[12];
    float idet = 1.0f / det;
    for (int i = 0; i < 16; i++) o[i] = inv[i] * idet;
}

__global__ __launch_bounds__(64) void render_k(
    const float* __restrict__ pixels,
    const float* __restrict__ Cm, const float* __restrict__ Wm, const float* __restrict__ Sm,
    const float* __restrict__ W1, const float* __restrict__ b1,
    const float* __restrict__ W2, const float* __restrict__ b2,
    const float* __restrict__ Wc1, const float* __restrict__ bc1,
    const float* __restrict__ Wc2, const float* __restrict__ bc2,
    float* __restrict__ out, int N)
{
    const int tid = threadIdx.x;      // 0..63, one wave
    const int r   = blockIdx.x;       // one ray per block

    // ray-dependent reparam LDS (pair-major): slot j2 = hidden units 2j2, 2j2+1
    __shared__ float4 sP0[H_/2];      // {a,a', c,c'}     occ, log2 domain
    __shared__ float4 sC [H_/2];      // {aC,aC', cC,cC'} color
    __shared__ float  sInv[3][16];    // iC, iW, iS
    __shared__ float  sT[16], sM[16];

    // ---- geometry: one inv4, matrices spread over lanes 0..2 ----
    {
        const float* mm = (tid == 0) ? Cm : ((tid == 1) ? Wm : Sm);
        float o[16];
        inv4(mm, o);                  // control-uniform; data-divergent
        if (tid < 3)
            for (int k = 0; k < 16; k++) sInv[tid][k] = o[k];
    }
    __syncthreads();
    if (tid < 16) {                   // T = iW @ iC
        int row = tid >> 2, col = tid & 3;
        float s = 0.0f;
        for (int k = 0; k < 4; k++) s += sInv[1][row*4 + k] * sInv[0][k*4 + col];
        sT[tid] = s;
    }
    __syncthreads();
    if (tid < 16) {                   // M = iS @ T
        int row = tid >> 2, col = tid & 3;
        float s = 0.0f;
        for (int k = 0; k < 4; k++) s += sInv[2][row*4 + k] * sT[k*4 + col];
        sM[tid] = s;
    }
    __syncthreads();

    float cx, cy, cz, rx, ry, rz, dfar;
    int mint;
    {
        const float px_ = pixels[2*r], py_ = pixels[2*r + 1];
        float cam[3], dir[3];
        for (int i = 0; i < 3; i++) {
            cam[i] = sM[4*i + 3];
            float pw = sM[4*i + 0]*px_ + sM[4*i + 1]*py_ + sM[4*i + 2] + sM[4*i + 3];
            dir[i] = pw - cam[i];
        }
        float nrm = sqrtf(dir[0]*dir[0] + dir[1]*dir[1] + dir[2]*dir[2]);
        rx = dir[0]/nrm; ry = dir[1]/nrm; rz = dir[2]/nrm;
        cx = cam[0]; cy = cam[1]; cz = cam[2];
        float rcd = rx*cx + ry*cy + rz*cz;
        float cc  = cx*cx + cy*cy + cz*cz;
        float under = rcd*rcd - (cc - 1.0f);      // RADIUS = 1
        mint = under > 0.0f;
        float s = sqrtf(mint ? under : 1.0f);
        dfar = mint ? fmaxf(s - rcd, 0.0f) : 0.0f;
    }

    // ---- staging + reparam: lane stages hidden units 2*tid, 2*tid+1 ----
    float a2k[2], c2k[2], w2k[2];               // occ (secant + fast path)
    float cCr[2], w0r[2], w1r[2], w2r[2];       // color (fast path)
    {
        const int u0 = 2 * tid;
        const float2 w1xv = ld2(W1 + u0);
        const float2 w1yv = ld2(W1 + H_ + u0);
        const float2 w1zv = ld2(W1 + 2*H_ + u0);
        const float2 b1v  = ld2(b1 + u0);
        const float2 w2v  = ld2(W2 + u0);
        a2k[0] = (w1xv.x*rx + w1yv.x*ry + w1zv.x*rz) * L2E;
        a2k[1] = (w1xv.y*rx + w1yv.y*ry + w1zv.y*rz) * L2E;
        c2k[0] = (w1xv.x*cx + w1yv.x*cy + w1zv.x*cz + b1v.x) * L2E;
        c2k[1] = (w1xv.y*cx + w1yv.y*cy + w1zv.y*cz + b1v.y) * L2E;
        w2k[0] = w2v.x * LN2;
        w2k[1] = w2v.y * LN2;
        const float2 q0v  = ld2(Wc1 + u0);
        const float2 q1v  = ld2(Wc1 + H_ + u0);
        const float2 q2v  = ld2(Wc1 + 2*H_ + u0);
        const float2 q3v  = ld2(Wc1 + 3*H_ + u0);
        const float2 q4v  = ld2(Wc1 + 4*H_ + u0);
        const float2 q5v  = ld2(Wc1 + 5*H_ + u0);
        const float2 bc1v = ld2(bc1 + u0);
        float aC0 = q0v.x*rx + q1v.x*ry + q2v.x*rz;
        float aC1 = q0v.y*rx + q1v.y*ry + q2v.y*rz;
        cCr[0] = q0v.x*cx + q1v.x*cy + q2v.x*cz + bc1v.x - (q3v.x*rx + q4v.x*ry + q5v.x*rz);
        cCr[1] = q0v.y*cx + q1v.y*cy + q2v.y*cz + bc1v.y - (q3v.y*rx + q4v.y*ry + q5v.y*rz);
        const float2 wc2a = ld2(Wc2 + 3*u0);      // {w0[0], w1[0]}
        const float2 wc2b = ld2(Wc2 + 3*u0 + 2);  // {w2[0], w0[1]}
        const float2 wc2c = ld2(Wc2 + 3*u0 + 4);  // {w1[1], w2[1]}
        w0r[0] = wc2a.x; w1r[0] = wc2a.y; w2r[0] = wc2b.x;
        w0r[1] = wc2b.y; w1r[1] = wc2c.x; w2r[1] = wc2c.y;
        sP0[tid] = float4{a2k[0], a2k[1], c2k[0], c2k[1]};
        sC [tid] = float4{aC0,    aC1,    cCr[0], cCr[1]};
    }
    const float b2v  = b2[0];
    const float bc20 = bc2[0], bc21 = bc2[1], bc22 = bc2[2];
    __syncthreads();

    float alpha0, r0c, g0c, b0c;      // sample tid
    float alpha1, r1c, g1c, b1c;      // sample 64 + (tid&31)

    if (rflf(dfar) == 0.0f) {         // scalar branch (dfar wave-uniform)
        // ---- fast path: all 96 samples sit at the camera point ----
        f2 sp = sp2p(f2{c2k[0], c2k[1]});
        float part = sp.x*w2k[0] + sp.y*w2k[1];
        f2 ff = __builtin_elementwise_max(f2{cCr[0], cCr[1]}, s2(0.0f));
        float A0 = ff.x*w0r[0] + ff.y*w0r[1];
        float A1 = ff.x*w1r[0] + ff.y*w1r[1];
        float A2 = ff.x*w2r[0] + ff.y*w2r[1];
#pragma unroll
        for (int off = 32; off; off >>= 1) {
            part += __shfl_xor(part, off, 64);
            A0   += __shfl_xor(A0,   off, 64);
            A1   += __shfl_xor(A1,   off, 64);
            A2   += __shfl_xor(A2,   off, 64);
        }
        alpha0 = sigmoid_fast(part + b2v);
        r0c = sigmoid_fast(A0 + bc20);
        g0c = sigmoid_fast(A1 + bc21);
        b0c = sigmoid_fast(A2 + bc22);
        alpha1 = alpha0; r1c = r0c; g1c = g0c; b1c = b0c;
    } else {
        const float inv127 = 1.0f / (RS - 1);

        // ---- phase 1a: logit at d=0 (p = camera; decides mask_0_free) ----
        float l0;
        {
            f2 sp = sp2p(f2{c2k[0], c2k[1]});
            float part = sp.x*w2k[0] + sp.y*w2k[1];
#pragma unroll
            for (int off = 32; off; off >>= 1) part += __shfl_xor(part, off, 64);
            l0 = part + b2v;
        }

        float d_i;
        if (rflf(l0) >= 0.0f) {       // scalar branch (l0 wave-uniform)
            // mask_0_free false -> d_i = 0, background sampling; skip march.
            d_i = 0.0f;
        } else {
            // occ logit at distance dsmp: 1 b128 LDS + W2 via uniform s_load
            auto march_logit = [&](float dsmp) -> float {
                const f2 dd = s2(dsmp);
                float ax = 0.0f, ay = 0.0f;
#pragma unroll 4
                for (int j2 = 0; j2 < H_/2; j2++) {
                    float4 q = sP0[j2];
                    float w2a = W2[2*j2], w2b = W2[2*j2 + 1];   // uniform -> s_load
                    f2 u = __builtin_elementwise_fma(f2{q.x, q.y}, dd, f2{q.z, q.w});
                    f2 sp = sp2p(u);
                    ax = fmaf(sp.x, w2a, ax);
                    ay = fmaf(sp.y, w2b, ay);
                }
                return LN2 * (ax + ay) + b2v;
            };

            // ---- phase 1b: steps 0..63, one per lane; crossing on logit sign ----
            float lA = march_logit(dfar * ((float)tid * inv127));
            float lan = __shfl_down(lA, 1, 64);
            float ca = (tid < 63) ? sgnf(lA * lan) * (float)(RS - tid) : 1.0f;
            float cmin = ca; int ind = tid;
#pragma unroll
            for (int off = 32; off; off >>= 1) {
                float c2 = __shfl_xor(cmin, off, 64);
                int   i2 = __shfl_xor(ind,  off, 64);
                if (c2 < cmin || (c2 == cmin && i2 < ind)) { cmin = c2; ind = i2; }
            }
            int crossed = cmin < 0.0f;            // wave-uniform
            float ll = 0.0f, lh = 0.0f;           // bracket logits
            if (rfli(crossed)) {
                ll = __shfl(lA, ind, 64);
                lh = __shfl(lA, ind + 1, 64);
            } else {
                // ---- phase 1c: steps 64..127 (only when half A is clean) ----
                float lB = march_logit(dfar * ((float)(tid + 64) * inv127));
                float l63 = __shfl(lA, 63, 64);
                float l64 = __shfl(lB, 0, 64);
                if (rflf(l63 * l64) < 0.0f) {     // boundary pair (63,64)
                    crossed = 1; ind = 63;
                    ll = l63; lh = l64;
                } else {
                    float lbn = __shfl_down(lB, 1, 64);
                    float cb = (tid < 63) ? sgnf(lB * lbn) * (float)(64 - tid) : 1.0f;
                    float cminb = cb; int indl = tid;
#pragma unroll
                    for (int off = 32; off; off >>= 1) {
                        float c2 = __shfl_xor(cminb, off, 64);
                        int   i2 = __shfl_xor(indl,  off, 64);
                        if (c2 < cminb || (c2 == cminb && i2 < indl)) { cminb = c2; indl = i2; }
                    }
                    if (rflf(cminb) < 0.0f) {
                        crossed = 1; ind = 64 + indl;
                        ll = __shfl(lB, indl, 64);
                        lh = __shfl(lB, indl + 1, 64);
                    }
                }
            }

            const int msk = crossed && (ll < 0.0f) && mint;
            if (rfli(msk)) {          // scalar branch; wave-uniform secant
                float f_l = sigmoid_fast(ll) - 0.5f;
                float f_h = sigmoid_fast(lh) - 0.5f;
                float d_l = dfar * ((float)ind * inv127);
                float d_h = dfar * ((float)(ind + 1) * inv127);
                float d_p = secant_step(f_l, f_h, d_l, d_h);
                for (int it = 0; it < NSEC; it++) {
                    f2 u2 = __builtin_elementwise_fma(f2{a2k[0], a2k[1]}, s2(d_p),
                                                      f2{c2k[0], c2k[1]});
                    f2 sp = sp2p(u2);
                    float part = sp.x*w2k[0] + sp.y*w2k[1];
#pragma unroll
                    for (int off = 32; off; off >>= 1) part += __shfl_xor(part, off, 64);
                    float fm = sigmoid_fast(part + b2v) - 0.5f;
                    bool low = fm < 0.0f;
                    d_l = low ? d_p : d_l;  f_l = low ? fm : f_l;
                    d_h = low ? d_h : d_p;  f_h = low ? f_h : fm;
                    d_p = secant_step(f_l, f_h, d_l, d_h);
                }
                d_i = d_p;
            } else {
                d_i = INFINITY;
            }
        }

        // ---- depth interval selection (matches reference d_i plumbing) ----
        const int mask_zero = (d_i == 0.0f);
        const int mask_pred = isfinite(d_i);
        float dists = mask_pred ? d_i : 1.0f;
        if (mask_zero) dists = 0.0f;
        const int obj = rfli(mask_pred && !mask_zero);   // wave-uniform
        const float dnp = fmaxf(dists - DELTA_, 0.0f);
        const float dfp = fminf(dists + DELTA_, dfar);

        auto sample_d = [&](int s) -> float {
            if (obj) {
                if (s < SOUT_) return dnp * ((float)s * (1.0f / (SOUT_ - 1)));
                float u = (float)(s - SOUT_) * (1.0f / (SIN_ - 1));
                return dnp * (1.0f - u) + dfp * u;
            }
            return dfar * ((float)s * (1.0f / (FULL_ - 1)));
        };

        // ---- phase 3, pass 0: samples 0..63; 2 b128 LDS + s_load weights ----
        {
            const f2 dd = s2(sample_d(tid));
            float SOx = 0.0f, SOy = 0.0f;
            float A0x = 0.0f, A0y = 0.0f, A1x = 0.0f, A1y = 0.0f, A2x = 0.0f, A2y = 0.0f;
#pragma unroll 4
            for (int j2 = 0; j2 < H_/2; j2++) {
                float4 q = sP0[j2];
                float4 c = sC[j2];
                float w2a = W2[2*j2], w2b = W2[2*j2 + 1];        // uniform -> s_load
                const float* wr = Wc2 + 6*j2;                    // uniform -> s_load
                f2 u = __builtin_elementwise_fma(f2{q.x, q.y}, dd, f2{q.z, q.w});
                f2 sp = sp2p(u);
                SOx = fmaf(sp.x, w2a, SOx);
                SOy = fmaf(sp.y, w2b, SOy);
                f2 fv = __builtin_elementwise_max(
                            __builtin_elementwise_fma(f2{c.x, c.y}, dd, f2{c.z, c.w}),
                            s2(0.0f));
                A0x = fmaf(fv.x, wr[0], A0x);
                A1x = fmaf(fv.x, wr[1], A1x);
                A2x = fmaf(fv.x, wr[2], A2x);
                A0y = fmaf(fv.y, wr[3], A0y);
                A1y = fmaf(fv.y, wr[4], A1y);
                A2y = fmaf(fv.y, wr[5], A2y);
            }
            alpha0 = sigmoid_fast(LN2 * (SOx + SOy) + b2v);
            r0c = sigmoid_fast(A0x + A0y + bc20);
            g0c = sigmoid_fast(A1x + A1y + bc21);
            b0c = sigmoid_fast(A2x + A2y + bc22);
        }

        // ---- phase 3, pass 1: samples 64..95; pair-range split by half-wave ----
        {
            const int s1 = 64 + (tid & 31);
            const int jb = (tid >> 5) * (H_/4);   // 0 or 32 pair-slots
            const f2 dd = s2(sample_d(s1));
            float SOx = 0.0f, SOy = 0.0f;
            float A0x = 0.0f, A0y = 0.0f, A1x = 0.0f, A1y = 0.0f, A2x = 0.0f, A2y = 0.0f;
#pragma unroll 4
            for (int j2 = jb; j2 < jb + H_/4; j2++) {
                float4 q = sP0[j2];
                float4 c = sC[j2];
                float w2a = W2[2*j2], w2b = W2[2*j2 + 1];
                const float* wr = Wc2 + 6*j2;
                f2 u = __builtin_elementwise_fma(f2{q.x, q.y}, dd, f2{q.z, q.w});
                f2 sp = sp2p(u);
                SOx = fmaf(sp.x, w2a, SOx);
                SOy = fmaf(sp.y, w2b, SOy);
                f2 fv = __builtin_elementwise_max(
                            __builtin_elementwise_fma(f2{c.x, c.y}, dd, f2{c.z, c.w}),
                            s2(0.0f));
                A0x = fmaf(fv.x, wr[0], A0x);
                A1x = fmaf(fv.x, wr[1], A1x);
                A2x = fmaf(fv.x, wr[2], A2x);
                A0y = fmaf(fv.y, wr[3], A0y);
                A1y = fmaf(fv.y, wr[4], A1y);
                A2y = fmaf(fv.y, wr[5], A2y);
            }
            float SOs = SOx + SOy;
            float A0s = A0x + A0y, A1s = A1x + A1y, A2s = A2x + A2y;
            SOs += __shfl_xor(SOs, 32, 64);
            A0s += __shfl_xor(A0s, 32, 64);
            A1s += __shfl_xor(A1s, 32, 64);
            A2s += __shfl_xor(A2s, 32, 64);
            alpha1 = sigmoid_fast(LN2 * SOs + b2v);
            r1c = sigmoid_fast(A0s + bc20);
            g1c = sigmoid_fast(A1s + bc21);
            b1c = sigmoid_fast(A2s + bc22);
        }
    }

    // ---- compositing: in-register wave scan over 96 ordered samples ----
    {
        float mA = 1.0f - alpha0 + EPSA;
        float p = mA;
#pragma unroll
        for (int off = 1; off < 64; off <<= 1) {
            float v = __shfl_up(p, off, 64);
            if (tid >= off) p *= v;
        }
        float TexA = __shfl_up(p, 1, 64);
        if (tid == 0) TexA = 1.0f;
        float TA = __shfl(p, 63, 64);
        float wA = alpha0 * TexA;

        float mB = (tid < 32) ? (1.0f - alpha1 + EPSA) : 1.0f;
        float pb = mB;
#pragma unroll
        for (int off = 1; off < 32; off <<= 1) {
            float v = __shfl_up(pb, off, 64);
            if (tid >= off) pb *= v;
        }
        float TexB = __shfl_up(pb, 1, 64);
        if (tid == 0) TexB = 1.0f;
        float wB = (tid < 32) ? alpha1 * TexB * TA : 0.0f;

        float s0 = wA*r0c + wB*r1c;
        float s1 = wA*g0c + wB*g1c;
        float s2v = wA*b0c + wB*b1c;
#pragma unroll
        for (int off = 32; off; off >>= 1) {
            s0  += __shfl_xor(s0,  off, 64);
            s1  += __shfl_xor(s1,  off, 64);
            s2v += __shfl_xor(s2v, off, 64);
        }
        if (tid == 0) {
            out[3*r + 0] = s0;
            out[3*r + 1] = s1;
            out[3*r + 2] = s2v;
        }
    }
}

} // namespace

extern "C" void kernel_launch(void* const* d_in, const int* in_sizes, int n_in,
                              void* d_out, int out_size, void* d_ws, size_t ws_size,
                              hipStream_t stream) {
    const float* pixels = (const float*)d_in[0];
    const float* Cm  = (const float*)d_in[1];
    const float* Wm  = (const float*)d_in[2];
    const float* Sm  = (const float*)d_in[3];
    const float* W1  = (const float*)d_in[4];
    const float* b1  = (const float*)d_in[5];
    const float* W2  = (const float*)d_in[6];
    const float* b2  = (const float*)d_in[7];
    const float* Wc1 = (const float*)d_in[8];
    const float* bc1 = (const float*)d_in[9];
    const float* Wc2 = (const float*)d_in[10];
    const float* bc2 = (const float*)d_in[11];
    float* out = (float*)d_out;

    const int N = in_sizes[0] / 2;   // pixels is (B=1, N, 2)
    hipLaunchKernelGGL(render_k, dim3(N), dim3(64), 0, stream,
                       pixels, Cm, Wm, Sm, W1, b1, W2, b2, Wc1, bc1, Wc2, bc2, out, N);
}

// Round 9
// 96.519 us; speedup vs baseline: 1.0229x; 1.0229x over previous
//
#include <hip/hip_runtime.h>
#include <math.h>

// Renderer: occupancy-field ray marching + secant + shading.
// R15: prologue hoist. Issue-bound model (confirmed by linear instr response
//     across R8-R14): remove redundant per-block work. (1) M = S^-1 W^-1 C^-1
//     computed ONCE by a 1-block prep kernel into d_ws (graph-safe enqueue);
//     render_k reads M via uniform s_loads -> drops inv4 (~200 instr) + two
//     matmuls + 3 barriers from every one of 4096 blocks. (2) staging reparams
//     pk-packed (f2 math, ~30 instr saved). (3) sW2 LDS table dropped; march
//     reads W2 as adjacent-pair uniform loads (s_load + pk_fma), LN2 folded
//     at the epilogue. Everything else bit-identical to R13 (best: 97.2).
// Carried from R13: hw-log softplus (exact, 7 instr), logit-sign crossing
//     search. Carried from R7: early-exit chunked march (l0 gate, half-A
//     first), dfar==0 fast path, in-register 96-sample compositing scan.

namespace {

constexpr int H_    = 128;
constexpr int RS    = 128;   // RAY_STEPS
constexpr int NSEC  = 8;
constexpr int SOUT_ = 32;    // STEPS_OUT
constexpr int SIN_  = 64;    // STEPS_IN
constexpr int FULL_ = 96;
constexpr float EPSA   = 1e-6f;
constexpr float DELTA_ = 0.44626032029685964f; // max(2*exp(-1.5), 0.1)
constexpr float L2E    = 1.4426950408889634f;  // log2(e)
constexpr float LN2    = 0.6931471805599453f;

typedef __attribute__((ext_vector_type(2))) float f2;

__device__ __forceinline__ f2 s2(float v) { return f2{v, v}; }

// packed log2-domain softplus: sp2(u) = max(u,0) + log2(1 + 2^-|u|)
// exact: e = 2^-|u| in (0,1], 1+e in (1,2], v_log_f32 is ~1ulp there.
__device__ __forceinline__ f2 sp2p(f2 u) {
    f2 e;
    e.x = __builtin_amdgcn_exp2f(-fabsf(u.x));
    e.y = __builtin_amdgcn_exp2f(-fabsf(u.y));
    f2 onep = e + 1.0f;
    f2 l;
    l.x = __builtin_amdgcn_logf(onep.x);   // v_log_f32 = log2
    l.y = __builtin_amdgcn_logf(onep.y);
    return __builtin_elementwise_max(u, s2(0.0f)) + l;
}

__device__ __forceinline__ float sigmoid_fast(float x) {
    return __builtin_amdgcn_rcpf(1.0f + __expf(-x));
}
__device__ __forceinline__ float sgnf(float p) {
    return (p > 0.0f) ? 1.0f : ((p < 0.0f) ? -1.0f : 0.0f);
}
__device__ __forceinline__ float secant_step(float f_l, float f_h, float d_l, float d_h) {
    float den = f_h - f_l;
    if (fabsf(den) > 1e-12f) return -f_l * (d_h - d_l) / den + d_l;
    return 0.5f * (d_l + d_h);
}
__device__ __forceinline__ float2 ld2(const float* p) {
    return *reinterpret_cast<const float2*>(p);
}
__device__ __forceinline__ f2 tf2(float2 v) { return f2{v.x, v.y}; }

__device__ void inv4(const float* m, float* o) {
    float inv[16];
    inv[0]  =  m[5]*m[10]*m[15] - m[5]*m[11]*m[14] - m[9]*m[6]*m[15] + m[9]*m[7]*m[14] + m[13]*m[6]*m[11] - m[13]*m[7]*m[10];
    inv[4]  = -m[4]*m[10]*m[15] + m[4]*m[11]*m[14] + m[8]*m[6]*m[15] - m[8]*m[7]*m[14] - m[12]*m[6]*m[11] + m[12]*m[7]*m[10];
    inv[8]  =  m[4]*m[9]*m[15]  - m[4]*m[11]*m[13] - m[8]*m[5]*m[15] + m[8]*m[7]*m[13] + m[12]*m[5]*m[11] - m[12]*m[7]*m[9];
    inv[12] = -m[4]*m[9]*m[14]  + m[4]*m[10]*m[13] + m[8]*m[5]*m[14] - m[8]*m[6]*m[13] - m[12]*m[5]*m[10] + m[12]*m[6]*m[9];
    inv[1]  = -m[1]*m[10]*m[15] + m[1]*m[11]*m[14] + m[9]*m[2]*m[15] - m[9]*m[3]*m[14] - m[13]*m[2]*m[11] + m[13]*m[3]*m[10];
    inv[5]  =  m[0]*m[10]*m[15] - m[0]*m[11]*m[14] - m[8]*m[2]*m[15] + m[8]*m[3]*m[14] + m[12]*m[2]*m[11] - m[12]*m[3]*m[10];
    inv[9]  = -m[0]*m[9]*m[15]  + m[0]*m[11]*m[13] + m[8]*m[1]*m[15] - m[8]*m[3]*m[13] - m[12]*m[1]*m[11] + m[12]*m[3]*m[9];
    inv[13] =  m[0]*m[9]*m[14]  - m[0]*m[10]*m[13] - m[8]*m[1]*m[14] + m[8]*m[2]*m[13] + m[12]*m[1]*m[10] - m[12]*m[2]*m[9];
    inv[2]  =  m[1]*m[6]*m[15]  - m[1]*m[7]*m[14]  - m[5]*m[2]*m[15] + m[5]*m[3]*m[14] + m[13]*m[2]*m[7]  - m[13]*m[3]*m[6];
    inv[6]  = -m[0]*m[6]*m[15]  + m[0]*m[7]*m[14]  + m[4]*m[2]*m[15] - m[4]*m[3]*m[14] - m[12]*m[2]*m[7]  + m[12]*m[3]*m[6];
    inv[10] =  m[0]*m[5]*m[15]  - m[0]*m[7]*m[13]  - m[4]*m[1]*m[15] + m[4]*m[3]*m[13] + m[12]*m[1]*m[7]  - m[12]*m[3]*m[5];
    inv[14] = -m[0]*m[5]*m[14]  + m[0]*m[6]*m[13]  + m[4]*m[1]*m[14] - m[4]*m[2]*m[13] - m[12]*m[1]*m[6]  + m[12]*m[2]*m[5];
    inv[3]  = -m[1]*m[6]*m[11]  + m[1]*m[7]*m[10]  + m[5]*m[2]*m[11] - m[5]*m[3]*m[10] - m[9]*m[2]*m[7]   + m[9]*m[3]*m[6];
    inv[7]  =  m[0]*m[6]*m[11]  - m[0]*m[7]*m[10]  - m[4]*m[2]*m[11] + m[4]*m[3]*m[10] + m[8]*m[2]*m[7]   - m[8]*m[3]*m[6];
    inv[11] = -m[0]*m[5]*m[11]  + m[0]*m[7]*m[9]   + m[4]*m[1]*m[11] - m[4]*m[3]*m[9]  - m[8]*m[1]*m[7]   + m[8]*m[3]*m[5];
    inv[15] =  m[0]*m[5]*m[10]  - m[0]*m[6]*m[9]   - m[4]*m[1]*m[10] + m[4]*m[2]*m[9]  + m[8]*m[1]*m[6]   - m[8]*m[2]*m[5];
    float det = m[0]*inv[0] + m[1]*inv[4] + m[2]*inv[8] + m[3]*inv[12];
    float idet = 1.0f / det;
    for (int i = 0; i < 16; i++) o[i] = inv[i] * idet;
}

// one-block setup: M = S^-1 @ W^-1 @ C^-1 -> d_ws[0..15]
__global__ __launch_bounds__(64) void prep_M(
    const float* __restrict__ Cm, const float* __restrict__ Wm,
    const float* __restrict__ Sm, float* __restrict__ Mout)
{
    const int tid = threadIdx.x;
    __shared__ float sInv[3][16];
    __shared__ float sT[16];
    if (tid < 3) {
        const float* mm = (tid == 0) ? Cm : ((tid == 1) ? Wm : Sm);
        float o[16];
        inv4(mm, o);
        for (int k = 0; k < 16; k++) sInv[tid][k] = o[k];
    }
    __syncthreads();
    if (tid < 16) {                   // T = iW @ iC
        int row = tid >> 2, col = tid & 3;
        float s = 0.0f;
        for (int k = 0; k < 4; k++) s += sInv[1][row*4 + k] * sInv[0][k*4 + col];
        sT[tid] = s;
    }
    __syncthreads();
    if (tid < 16) {                   // M = iS @ T
        int row = tid >> 2, col = tid & 3;
        float s = 0.0f;
        for (int k = 0; k < 4; k++) s += sInv[2][row*4 + k] * sT[k*4 + col];
        Mout[tid] = s;
    }
}

__global__ __launch_bounds__(64) void render_k(
    const float* __restrict__ pixels,
    const float* __restrict__ Mws,
    const float* __restrict__ W1, const float* __restrict__ b1,
    const float* __restrict__ W2, const float* __restrict__ b2,
    const float* __restrict__ Wc1, const float* __restrict__ bc1,
    const float* __restrict__ Wc2, const float* __restrict__ bc2,
    float* __restrict__ out, int N)
{
    const int tid = threadIdx.x;      // 0..63, one wave
    const int r   = blockIdx.x;       // one ray per block

    // pair-major weight LDS: slot j2 holds hidden units 2*j2, 2*j2+1
    __shared__ float4 sP0[H_/2];      // {a,a', c,c'}       (occ, log2 domain)
    __shared__ float4 sP1[H_/2];      // {w,w', aC,aC'}     (w = w2*ln2)
    __shared__ float4 sP2[H_/2];      // {cC,cC', w0,w0'}
    __shared__ float4 sP3[H_/2];      // {w1,w1', w2,w2'}

    // ---- per-ray geometry from precomputed M (uniform s_loads) ----
    float cx, cy, cz, rx, ry, rz, dfar;
    int mint;
    {
        const float px_ = pixels[2*r], py_ = pixels[2*r + 1];
        float cam[3], dir[3];
        for (int i = 0; i < 3; i++) {
            cam[i] = Mws[4*i + 3];
            float pw = Mws[4*i + 0]*px_ + Mws[4*i + 1]*py_ + Mws[4*i + 2] + Mws[4*i + 3];
            dir[i] = pw - cam[i];
        }
        float nrm = sqrtf(dir[0]*dir[0] + dir[1]*dir[1] + dir[2]*dir[2]);
        rx = dir[0]/nrm; ry = dir[1]/nrm; rz = dir[2]/nrm;
        cx = cam[0]; cy = cam[1]; cz = cam[2];
        float rcd = rx*cx + ry*cy + rz*cz;
        float cc  = cx*cx + cy*cy + cz*cz;
        float under = rcd*rcd - (cc - 1.0f);      // RADIUS = 1
        mint = under > 0.0f;
        float s = sqrtf(mint ? under : 1.0f);
        dfar = mint ? fmaxf(s - rcd, 0.0f) : 0.0f;
    }

    // ---- staging + reparam (pk-packed): lane stages units 2*tid, 2*tid+1 ----
    float a2k[2], c2k[2], w2k[2];               // occ (secant + fast path)
    float cCr[2], w0r[2], w1r[2], w2r[2];       // color (fast path)
    {
        const int u0 = 2 * tid;
        const f2 w1x = tf2(ld2(W1 + u0));
        const f2 w1y = tf2(ld2(W1 + H_ + u0));
        const f2 w1z = tf2(ld2(W1 + 2*H_ + u0));
        const f2 b1v = tf2(ld2(b1 + u0));
        const f2 w2v = tf2(ld2(W2 + u0));
        f2 a2f = __builtin_elementwise_fma(w1z, s2(rz),
                 __builtin_elementwise_fma(w1y, s2(ry), w1x * s2(rx))) * s2(L2E);
        f2 c2f = (__builtin_elementwise_fma(w1z, s2(cz),
                  __builtin_elementwise_fma(w1y, s2(cy), w1x * s2(cx))) + b1v) * s2(L2E);
        f2 w2f = w2v * s2(LN2);
        a2k[0] = a2f.x; a2k[1] = a2f.y;
        c2k[0] = c2f.x; c2k[1] = c2f.y;
        w2k[0] = w2f.x; w2k[1] = w2f.y;
        const f2 q0 = tf2(ld2(Wc1 + u0));
        const f2 q1 = tf2(ld2(Wc1 + H_ + u0));
        const f2 q2 = tf2(ld2(Wc1 + 2*H_ + u0));
        const f2 q3 = tf2(ld2(Wc1 + 3*H_ + u0));
        const f2 q4 = tf2(ld2(Wc1 + 4*H_ + u0));
        const f2 q5 = tf2(ld2(Wc1 + 5*H_ + u0));
        const f2 bc1v = tf2(ld2(bc1 + u0));
        f2 aCf = __builtin_elementwise_fma(q2, s2(rz),
                 __builtin_elementwise_fma(q1, s2(ry), q0 * s2(rx)));
        f2 cCf = __builtin_elementwise_fma(q2, s2(cz),
                 __builtin_elementwise_fma(q1, s2(cy), q0 * s2(cx))) + bc1v
               - __builtin_elementwise_fma(q5, s2(rz),
                 __builtin_elementwise_fma(q4, s2(ry), q3 * s2(rx)));
        cCr[0] = cCf.x; cCr[1] = cCf.y;
        const float2 wc2a = ld2(Wc2 + 3*u0);      // {w0[0], w1[0]}
        const float2 wc2b = ld2(Wc2 + 3*u0 + 2);  // {w2[0], w0[1]}
        const float2 wc2c = ld2(Wc2 + 3*u0 + 4);  // {w1[1], w2[1]}
        w0r[0] = wc2a.x; w1r[0] = wc2a.y; w2r[0] = wc2b.x;
        w0r[1] = wc2b.y; w1r[1] = wc2c.x; w2r[1] = wc2c.y;
        sP0[tid] = float4{a2f.x, a2f.y, c2f.x, c2f.y};
        sP1[tid] = float4{w2f.x, w2f.y, aCf.x, aCf.y};
        sP2[tid] = float4{cCf.x, cCf.y, w0r[0], w0r[1]};
        sP3[tid] = float4{w1r[0], w1r[1], w2r[0], w2r[1]};
    }
    const float b2v  = b2[0];
    const float bc20 = bc2[0], bc21 = bc2[1], bc22 = bc2[2];
    __syncthreads();

    float alpha0, r0c, g0c, b0c;      // sample tid
    float alpha1, r1c, g1c, b1c;      // sample 64 + (tid&31)

    if (dfar == 0.0f) {
        // ---- fast path: all 96 samples sit at the camera point ----
        f2 sp = sp2p(f2{c2k[0], c2k[1]});
        float part = sp.x*w2k[0] + sp.y*w2k[1];
        f2 ff = __builtin_elementwise_max(f2{cCr[0], cCr[1]}, s2(0.0f));
        float A0 = ff.x*w0r[0] + ff.y*w0r[1];
        float A1 = ff.x*w1r[0] + ff.y*w1r[1];
        float A2 = ff.x*w2r[0] + ff.y*w2r[1];
#pragma unroll
        for (int off = 32; off; off >>= 1) {
            part += __shfl_xor(part, off, 64);
            A0   += __shfl_xor(A0,   off, 64);
            A1   += __shfl_xor(A1,   off, 64);
            A2   += __shfl_xor(A2,   off, 64);
        }
        alpha0 = sigmoid_fast(part + b2v);
        r0c = sigmoid_fast(A0 + bc20);
        g0c = sigmoid_fast(A1 + bc21);
        b0c = sigmoid_fast(A2 + bc22);
        alpha1 = alpha0; r1c = r0c; g1c = g0c; b1c = b0c;
    } else {
        const float inv127 = 1.0f / (RS - 1);

        // ---- phase 1a: logit at d=0 (p = camera; decides mask_0_free) ----
        float l0;
        {
            f2 sp = sp2p(f2{c2k[0], c2k[1]});
            float part = sp.x*w2k[0] + sp.y*w2k[1];
#pragma unroll
            for (int off = 32; off; off >>= 1) part += __shfl_xor(part, off, 64);
            l0 = part + b2v;
        }

        float d_i;
        if (l0 >= 0.0f) {
            // mask_0_free false -> d_i = 0, background sampling; skip march.
            d_i = 0.0f;
        } else {
            // occ logit at distance dsmp: sP0 b128 + W2 adjacent-pair uniform load
            auto march_logit = [&](float dsmp) -> float {
                const f2 dd = s2(dsmp);
                f2 acc = s2(0.0f);
#pragma unroll 4
                for (int j2 = 0; j2 < H_/2; j2++) {
                    float4 q0 = sP0[j2];
                    const float2 wv = ld2(W2 + 2*j2);     // uniform -> s_load
                    f2 u = __builtin_elementwise_fma(f2{q0.x, q0.y}, dd, f2{q0.z, q0.w});
                    acc = __builtin_elementwise_fma(sp2p(u), f2{wv.x, wv.y}, acc);
                }
                return LN2 * (acc.x + acc.y) + b2v;
            };

            // ---- phase 1b: steps 0..63, one per lane; crossing on logit sign ----
            float lA = march_logit(dfar * ((float)tid * inv127));
            float lan = __shfl_down(lA, 1, 64);
            float ca = (tid < 63) ? sgnf(lA * lan) * (float)(RS - tid) : 1.0f;
            float cmin = ca; int ind = tid;
#pragma unroll
            for (int off = 32; off; off >>= 1) {
                float c2 = __shfl_xor(cmin, off, 64);
                int   i2 = __shfl_xor(ind,  off, 64);
                if (c2 < cmin || (c2 == cmin && i2 < ind)) { cmin = c2; ind = i2; }
            }
            int crossed = cmin < 0.0f;            // wave-uniform
            float ll = 0.0f, lh = 0.0f;           // bracket logits
            if (crossed) {
                ll = __shfl(lA, ind, 64);
                lh = __shfl(lA, ind + 1, 64);
            } else {
                // ---- phase 1c: steps 64..127 (only when half A is clean) ----
                float lB = march_logit(dfar * ((float)(tid + 64) * inv127));
                float l63 = __shfl(lA, 63, 64);
                float l64 = __shfl(lB, 0, 64);
                if (l63 * l64 < 0.0f) {           // boundary pair (63,64)
                    crossed = 1; ind = 63;
                    ll = l63; lh = l64;
                } else {
                    float lbn = __shfl_down(lB, 1, 64);
                    float cb = (tid < 63) ? sgnf(lB * lbn) * (float)(64 - tid) : 1.0f;
                    float cminb = cb; int indl = tid;
#pragma unroll
                    for (int off = 32; off; off >>= 1) {
                        float c2 = __shfl_xor(cminb, off, 64);
                        int   i2 = __shfl_xor(indl,  off, 64);
                        if (c2 < cminb || (c2 == cminb && i2 < indl)) { cminb = c2; indl = i2; }
                    }
                    if (cminb < 0.0f) {
                        crossed = 1; ind = 64 + indl;
                        ll = __shfl(lB, indl, 64);
                        lh = __shfl(lB, indl + 1, 64);
                    }
                }
            }

            const int msk = crossed && (ll < 0.0f) && mint;
            if (msk) {   // wave-uniform secant refinement
                float f_l = sigmoid_fast(ll) - 0.5f;
                float f_h = sigmoid_fast(lh) - 0.5f;
                float d_l = dfar * ((float)ind * inv127);
                float d_h = dfar * ((float)(ind + 1) * inv127);
                float d_p = secant_step(f_l, f_h, d_l, d_h);
                for (int it = 0; it < NSEC; it++) {
                    f2 u2 = __builtin_elementwise_fma(f2{a2k[0], a2k[1]}, s2(d_p),
                                                      f2{c2k[0], c2k[1]});
                    f2 sp = sp2p(u2);
                    float part = sp.x*w2k[0] + sp.y*w2k[1];
#pragma unroll
                    for (int off = 32; off; off >>= 1) part += __shfl_xor(part, off, 64);
                    float fm = sigmoid_fast(part + b2v) - 0.5f;
                    bool low = fm < 0.0f;
                    d_l = low ? d_p : d_l;  f_l = low ? fm : f_l;
                    d_h = low ? d_h : d_p;  f_h = low ? f_h : fm;
                    d_p = secant_step(f_l, f_h, d_l, d_h);
                }
                d_i = d_p;
            } else {
                d_i = INFINITY;
            }
        }

        // ---- depth interval selection (matches reference d_i plumbing) ----
        const int mask_zero = (d_i == 0.0f);
        const int mask_pred = isfinite(d_i);
        float dists = mask_pred ? d_i : 1.0f;
        if (mask_zero) dists = 0.0f;
        const int obj = mask_pred && !mask_zero;
        const float dnp = fmaxf(dists - DELTA_, 0.0f);
        const float dfp = fminf(dists + DELTA_, dfar);

        auto sample_d = [&](int s) -> float {
            if (obj) {
                if (s < SOUT_) return dnp * ((float)s * (1.0f / (SOUT_ - 1)));
                float u = (float)(s - SOUT_) * (1.0f / (SIN_ - 1));
                return dnp * (1.0f - u) + dfp * u;
            }
            return dfar * ((float)s * (1.0f / (FULL_ - 1)));
        };

        // ---- phase 3, pass 0: samples 0..63, hidden units paired ----
        {
            const f2 dd = s2(sample_d(tid));
            f2 SO = s2(0.0f), A0 = s2(0.0f), A1 = s2(0.0f), A2 = s2(0.0f);
#pragma unroll 4
            for (int j2 = 0; j2 < H_/2; j2++) {
                float4 q0 = sP0[j2];
                float4 q1 = sP1[j2];
                float4 q2 = sP2[j2];
                float4 q3 = sP3[j2];
                f2 u = __builtin_elementwise_fma(f2{q0.x, q0.y}, dd, f2{q0.z, q0.w});
                SO = __builtin_elementwise_fma(sp2p(u), f2{q1.x, q1.y}, SO);
                f2 f = __builtin_elementwise_max(
                           __builtin_elementwise_fma(f2{q1.z, q1.w}, dd, f2{q2.x, q2.y}),
                           s2(0.0f));
                A0 = __builtin_elementwise_fma(f, f2{q2.z, q2.w}, A0);
                A1 = __builtin_elementwise_fma(f, f2{q3.x, q3.y}, A1);
                A2 = __builtin_elementwise_fma(f, f2{q3.z, q3.w}, A2);
            }
            alpha0 = sigmoid_fast(SO.x + SO.y + b2v);
            r0c = sigmoid_fast(A0.x + A0.y + bc20);
            g0c = sigmoid_fast(A1.x + A1.y + bc21);
            b0c = sigmoid_fast(A2.x + A2.y + bc22);
        }

        // ---- phase 3, pass 1: samples 64..95; pair-range split by half-wave ----
        {
            const int s1 = 64 + (tid & 31);
            const int jb = (tid >> 5) * (H_/4);   // 0 or 32 pair-slots
            const f2 dd = s2(sample_d(s1));
            f2 SO = s2(0.0f), A0 = s2(0.0f), A1 = s2(0.0f), A2 = s2(0.0f);
#pragma unroll 4
            for (int j2 = jb; j2 < jb + H_/4; j2++) {
                float4 q0 = sP0[j2];
                float4 q1 = sP1[j2];
                float4 q2 = sP2[j2];
                float4 q3 = sP3[j2];
                f2 u = __builtin_elementwise_fma(f2{q0.x, q0.y}, dd, f2{q0.z, q0.w});
                SO = __builtin_elementwise_fma(sp2p(u), f2{q1.x, q1.y}, SO);
                f2 f = __builtin_elementwise_max(
                           __builtin_elementwise_fma(f2{q1.z, q1.w}, dd, f2{q2.x, q2.y}),
                           s2(0.0f));
                A0 = __builtin_elementwise_fma(f, f2{q2.z, q2.w}, A0);
                A1 = __builtin_elementwise_fma(f, f2{q3.x, q3.y}, A1);
                A2 = __builtin_elementwise_fma(f, f2{q3.z, q3.w}, A2);
            }
            float SOs = SO.x + SO.y, A0s = A0.x + A0.y;
            float A1s = A1.x + A1.y, A2s = A2.x + A2.y;
            SOs += __shfl_xor(SOs, 32, 64);
            A0s += __shfl_xor(A0s, 32, 64);
            A1s += __shfl_xor(A1s, 32, 64);
            A2s += __shfl_xor(A2s, 32, 64);
            alpha1 = sigmoid_fast(SOs + b2v);
            r1c = sigmoid_fast(A0s + bc20);
            g1c = sigmoid_fast(A1s + bc21);
            b1c = sigmoid_fast(A2s + bc22);
        }
    }

    // ---- compositing: in-register wave scan over 96 ordered samples ----
    {
        float mA = 1.0f - alpha0 + EPSA;
        float p = mA;
#pragma unroll
        for (int off = 1; off < 64; off <<= 1) {
            float v = __shfl_up(p, off, 64);
            if (tid >= off) p *= v;
        }
        float TexA = __shfl_up(p, 1, 64);
        if (tid == 0) TexA = 1.0f;
        float TA = __shfl(p, 63, 64);
        float wA = alpha0 * TexA;

        float mB = (tid < 32) ? (1.0f - alpha1 + EPSA) : 1.0f;
        float pb = mB;
#pragma unroll
        for (int off = 1; off < 32; off <<= 1) {
            float v = __shfl_up(pb, off, 64);
            if (tid >= off) pb *= v;
        }
        float TexB = __shfl_up(pb, 1, 64);
        if (tid == 0) TexB = 1.0f;
        float wB = (tid < 32) ? alpha1 * TexB * TA : 0.0f;

        float s0 = wA*r0c + wB*r1c;
        float s1 = wA*g0c + wB*g1c;
        float s2v = wA*b0c + wB*b1c;
#pragma unroll
        for (int off = 32; off; off >>= 1) {
            s0  += __shfl_xor(s0,  off, 64);
            s1  += __shfl_xor(s1,  off, 64);
            s2v += __shfl_xor(s2v, off, 64);
        }
        if (tid == 0) {
            out[3*r + 0] = s0;
            out[3*r + 1] = s1;
            out[3*r + 2] = s2v;
        }
    }
}

} // namespace

extern "C" void kernel_launch(void* const* d_in, const int* in_sizes, int n_in,
                              void* d_out, int out_size, void* d_ws, size_t ws_size,
                              hipStream_t stream) {
    const float* pixels = (const float*)d_in[0];
    const float* Cm  = (const float*)d_in[1];
    const float* Wm  = (const float*)d_in[2];
    const float* Sm  = (const float*)d_in[3];
    const float* W1  = (const float*)d_in[4];
    const float* b1  = (const float*)d_in[5];
    const float* W2  = (const float*)d_in[6];
    const float* b2  = (const float*)d_in[7];
    const float* Wc1 = (const float*)d_in[8];
    const float* bc1 = (const float*)d_in[9];
    const float* Wc2 = (const float*)d_in[10];
    const float* bc2 = (const float*)d_in[11];
    float* out = (float*)d_out;
    float* Mws = (float*)d_ws;       // 16 floats; workspace is re-poisoned per
                                     // run, so prep_M re-runs in-graph each replay

    const int N = in_sizes[0] / 2;   // pixels is (B=1, N, 2)
    hipLaunchKernelGGL(prep_M, dim3(1), dim3(64), 0, stream, Cm, Wm, Sm, Mws);
    hipLaunchKernelGGL(render_k, dim3(N), dim3(64), 0, stream,
                       pixels, Mws, W1, b1, W2, b2, Wc1, bc1, Wc2, bc2, out, N);
}